// Round 1
// baseline (160.997 us; speedup 1.0000x reference)
//
#include <hip/hip_runtime.h>
#include <math.h>

#define LQ 4096
#define DQ 64
#define BQ 32
#define KSQ 25
#define PADQ 12
#define LN_EPS 1e-5f

// ws layout (floats):
// [0] alpha, [1] beta, [2] gamma
// [3..8] Mxx, Mss, Mcc, Mxs, Mxc, Msc
// [16..79] u, [80..143] v, [144..207] w
// [256 .. 256+4*4096)      Fu, Fv, Fw, FB
// [16640 .. 16640+32*4096) mean_corr
// [147712 .. +32*4)        per-b: lag0, lag1, w0, w1
#define WS_U   16
#define WS_V   80
#define WS_W   144
#define WS_F   256
#define WS_MC  (256 + 4 * LQ)
#define WS_TOP (WS_MC + BQ * LQ)

__device__ __forceinline__ float wave_sum64(float v) {
    for (int o = 32; o > 0; o >>= 1) v += __shfl_xor(v, o, 64);
    return v;
}

// ---------------- kernel 1: weight-derived scalars/vectors (1 block, 64 thr)
__global__ void ac_prep_kernel(const float* __restrict__ embed_w,
                               const float* __restrict__ embed_b,
                               const float* __restrict__ q_w, const float* __restrict__ q_b,
                               const float* __restrict__ k_w, const float* __restrict__ k_b,
                               const float* __restrict__ v_w, const float* __restrict__ v_b,
                               const float* __restrict__ ln_g,
                               float* __restrict__ ws) {
    int d = threadIdx.x; // 0..63
    float Aq = 0.f, Cq = 0.f, Ak = 0.f, Ck = 0.f, Av = 0.f, Cv = 0.f;
    for (int e = 0; e < DQ; ++e) {
        float we = embed_w[e], be = embed_b[e];
        float qw = q_w[e * DQ + d], kw = k_w[e * DQ + d], vw = v_w[e * DQ + d];
        Aq = fmaf(we, qw, Aq); Cq = fmaf(be, qw, Cq);
        Ak = fmaf(we, kw, Ak); Ck = fmaf(be, kw, Ck);
        Av = fmaf(we, vw, Av); Cv = fmaf(be, vw, Cv);
    }
    Cq += q_b[d]; Ck += k_b[d]; Cv += v_b[d];

    // z = x*cx + xs*cs + cc
    float cx = embed_w[d];
    float cs = Av;
    float cc = embed_b[d] + Cv;

    const float invD = 1.f / (float)DQ;
    float mx = wave_sum64(cx) * invD;
    float ms = wave_sum64(cs) * invD;
    float mc = wave_sum64(cc) * invD;
    float cxp = cx - mx, csp = cs - ms, ccp = cc - mc;

    float Mxx = wave_sum64(cxp * cxp) * invD;
    float Mss = wave_sum64(csp * csp) * invD;
    float Mcc = wave_sum64(ccp * ccp) * invD;
    float Mxs = wave_sum64(cxp * csp) * invD;
    float Mxc = wave_sum64(cxp * ccp) * invD;
    float Msc = wave_sum64(csp * ccp) * invD;

    float alpha = wave_sum64(Aq * Ak) * invD;
    float beta  = wave_sum64(Aq * Ck + Ak * Cq) * invD;
    float gamma = wave_sum64(Cq * Ck) * ((float)LQ * invD);

    float g = ln_g[d];
    ws[WS_U + d] = cxp * g;
    ws[WS_V + d] = csp * g;
    ws[WS_W + d] = ccp * g;
    if (d == 0) {
        ws[0] = alpha; ws[1] = beta; ws[2] = gamma;
        ws[3] = Mxx; ws[4] = Mss; ws[5] = Mcc;
        ws[6] = Mxs; ws[7] = Mxc; ws[8] = Msc;
    }
}

// ---------------- kernel 2: F arrays (grid 16 x 256)
__global__ void ac_prepF_kernel(const float* __restrict__ fc_w,
                                const float* __restrict__ ln_b,
                                float* __restrict__ ws) {
    __shared__ float su[DQ], sv[DQ], sw[DQ], sb[DQ];
    if (threadIdx.x < DQ) {
        su[threadIdx.x] = ws[WS_U + threadIdx.x];
        sv[threadIdx.x] = ws[WS_V + threadIdx.x];
        sw[threadIdx.x] = ws[WS_W + threadIdx.x];
        sb[threadIdx.x] = ln_b[threadIdx.x];
    }
    __syncthreads();
    int l = blockIdx.x * 256 + threadIdx.x;
    const float4* fc = (const float4*)(fc_w + (size_t)l * DQ);
    float fu = 0.f, fv = 0.f, fw = 0.f, fb = 0.f;
#pragma unroll
    for (int d4 = 0; d4 < DQ / 4; ++d4) {
        float4 f = fc[d4];
        int d = d4 * 4;
        fu = fmaf(su[d], f.x, fu); fu = fmaf(su[d+1], f.y, fu); fu = fmaf(su[d+2], f.z, fu); fu = fmaf(su[d+3], f.w, fu);
        fv = fmaf(sv[d], f.x, fv); fv = fmaf(sv[d+1], f.y, fv); fv = fmaf(sv[d+2], f.z, fv); fv = fmaf(sv[d+3], f.w, fv);
        fw = fmaf(sw[d], f.x, fw); fw = fmaf(sw[d+1], f.y, fw); fw = fmaf(sw[d+2], f.z, fw); fw = fmaf(sw[d+3], f.w, fw);
        fb = fmaf(sb[d], f.x, fb); fb = fmaf(sb[d+1], f.y, fb); fb = fmaf(sb[d+2], f.z, fb); fb = fmaf(sb[d+3], f.w, fb);
    }
    ws[WS_F + l]          = fu;
    ws[WS_F + LQ + l]     = fv;
    ws[WS_F + 2 * LQ + l] = fw;
    ws[WS_F + 3 * LQ + l] = fb;
}

// ---------------- kernel 3: circular autocorrelation -> mean_corr
// grid (B, 9): blocks y=0..7 cover lags 0..2047 (256 lags each), block y=8 does lag 2048.
// mean_corr[L-l] = mean_corr[l] by exact symmetry.
__global__ void ac_autocorr_kernel(const float* __restrict__ x,
                                   float* __restrict__ ws) {
    __shared__ float x2[2 * LQ];
    __shared__ float sred[256];
    int b = blockIdx.x;
    const float* xb = x + (size_t)b * LQ;
    float s = 0.f;
    for (int i = threadIdx.x; i < LQ; i += 256) {
        float v = xb[i];
        x2[i] = v; x2[i + LQ] = v;
        s += v;
    }
    sred[threadIdx.x] = s;
    __syncthreads();
    for (int st = 128; st > 0; st >>= 1) {
        if (threadIdx.x < st) sred[threadIdx.x] += sred[threadIdx.x + st];
        __syncthreads();
    }
    float Sx = sred[0];

    int lag; bool active = true;
    if (blockIdx.y < 8) lag = blockIdx.y * 256 + threadIdx.x;
    else { lag = 2048; active = (threadIdx.x == 0); }

    if (active) {
        int off = LQ - lag; // in [2048, 4096]
        float a0 = 0.f, a1 = 0.f, a2 = 0.f, a3 = 0.f;
        for (int t = 0; t < LQ; t += 4) {
            float4 xt = *(const float4*)&x2[t];   // broadcast, aligned
            a0 = fmaf(xt.x, x2[t + off],     a0);
            a1 = fmaf(xt.y, x2[t + 1 + off], a1);
            a2 = fmaf(xt.z, x2[t + 2 + off], a2);
            a3 = fmaf(xt.w, x2[t + 3 + off], a3);
        }
        float R = (a0 + a1) + (a2 + a3);
        float alpha = ws[0], beta = ws[1], gamma = ws[2];
        float v = fmaf(alpha, R, fmaf(beta, Sx, gamma));
        float* mc = ws + WS_MC + (size_t)b * LQ;
        mc[lag] = v;
        mc[(LQ - lag) & (LQ - 1)] = v;
    }
}

// ---------------- kernel 4: top-2 + softmax weights (grid B, 256 thr)
__device__ __forceinline__ bool ac_better(float v, int i, float v2, int i2) {
    return (v > v2) || (v == v2 && i < i2);
}
__global__ void ac_top2_kernel(float* __restrict__ ws) {
    int b = blockIdx.x;
    const float* mc = ws + WS_MC + (size_t)b * LQ;
    float v0 = -3.0e38f, v1 = -3.0e38f;
    int i0 = 1 << 30, i1 = 1 << 30;
    for (int l = threadIdx.x; l < LQ; l += 256) {
        float v = mc[l];
        if (ac_better(v, l, v0, i0)) { v1 = v0; i1 = i0; v0 = v; i0 = l; }
        else if (ac_better(v, l, v1, i1)) { v1 = v; i1 = l; }
    }
    __shared__ float sv0[256], sv1[256];
    __shared__ int   si0[256], si1[256];
    sv0[threadIdx.x] = v0; sv1[threadIdx.x] = v1;
    si0[threadIdx.x] = i0; si1[threadIdx.x] = i1;
    __syncthreads();
    for (int st = 128; st > 0; st >>= 1) {
        if (threadIdx.x < st) {
            float a0 = sv0[threadIdx.x], a1 = sv1[threadIdx.x];
            int   c0 = si0[threadIdx.x], c1 = si1[threadIdx.x];
            float u0 = sv0[threadIdx.x + st], u1 = sv1[threadIdx.x + st];
            int   j0 = si0[threadIdx.x + st], j1 = si1[threadIdx.x + st];
            float t0, t1; int t0i, t1i;
            if (ac_better(a0, c0, u0, j0)) {
                t0 = a0; t0i = c0;
                if (ac_better(u0, j0, a1, c1)) { t1 = u0; t1i = j0; } else { t1 = a1; t1i = c1; }
            } else {
                t0 = u0; t0i = j0;
                if (ac_better(a0, c0, u1, j1)) { t1 = a0; t1i = c0; } else { t1 = u1; t1i = j1; }
            }
            sv0[threadIdx.x] = t0; si0[threadIdx.x] = t0i;
            sv1[threadIdx.x] = t1; si1[threadIdx.x] = t1i;
        }
        __syncthreads();
    }
    if (threadIdx.x == 0) {
        float w0 = 1.f / (1.f + expf(sv1[0] - sv0[0]));
        float* top = ws + WS_TOP + b * 4;
        top[0] = (float)si0[0]; top[1] = (float)si1[0];
        top[2] = w0; top[3] = 1.f - w0;
    }
}

// ---------------- kernel 5: LN scalars + moving-avg + FC reduce (grid B, 256 thr)
__global__ void ac_final_kernel(const float* __restrict__ x,
                                const float* __restrict__ fc_b,
                                const float* __restrict__ ws,
                                float* __restrict__ out) {
    __shared__ float pL[LQ], qL[LQ], rL[LQ];
    __shared__ float red[256];
    int b = blockIdx.x;
    const float* xb = x + (size_t)b * LQ;
    const float* top = ws + WS_TOP + b * 4;
    int lag0 = (int)top[0], lag1 = (int)top[1];
    float w0 = top[2], w1 = top[3];
    float Mxx = ws[3], Mss = ws[4], Mcc = ws[5], Mxs = ws[6], Mxc = ws[7], Msc = ws[8];

    for (int l = threadIdx.x; l < LQ; l += 256) {
        float xv = xb[l];
        float xs = w0 * xb[(l - lag0) & (LQ - 1)] + w1 * xb[(l - lag1) & (LQ - 1)];
        float var = xv * xv * Mxx + xs * xs * Mss + Mcc
                  + 2.f * xv * xs * Mxs + 2.f * xv * Mxc + 2.f * xs * Msc;
        float r = rsqrtf(var + LN_EPS);
        pL[l] = xv * r; qL[l] = xs * r; rL[l] = r;
    }
    __syncthreads();

    const float* Fu = ws + WS_F;
    const float* Fv = Fu + LQ;
    const float* Fw = Fv + LQ;
    const float* FB = Fw + LQ;
    const float inv = 1.f / (float)KSQ;
    float acc = 0.f;
    for (int l = threadIdx.x; l < LQ; l += 256) {
        int lo = l - PADQ; if (lo < 0) lo = 0;
        int hi = l + PADQ; if (hi > LQ - 1) hi = LQ - 1;
        float sp = 0.f, sq = 0.f, sr = 0.f;
        for (int j = lo; j <= hi; ++j) { sp += pL[j]; sq += qL[j]; sr += rL[j]; }
        float cnt = (float)(hi - lo + 1);
        acc += (pL[l] - sp * inv) * Fu[l]
             + (qL[l] - sq * inv) * Fv[l]
             + (rL[l] - sr * inv) * Fw[l]
             + (1.f - cnt * inv) * FB[l];
    }
    red[threadIdx.x] = acc;
    __syncthreads();
    for (int st = 128; st > 0; st >>= 1) {
        if (threadIdx.x < st) red[threadIdx.x] += red[threadIdx.x + st];
        __syncthreads();
    }
    if (threadIdx.x == 0) out[b] = red[0] + fc_b[0];
}

extern "C" void kernel_launch(void* const* d_in, const int* in_sizes, int n_in,
                              void* d_out, int out_size, void* d_ws, size_t ws_size,
                              hipStream_t stream) {
    const float* x       = (const float*)d_in[0];
    const float* embed_w = (const float*)d_in[1];
    const float* embed_b = (const float*)d_in[2];
    const float* q_w     = (const float*)d_in[3];
    const float* q_b     = (const float*)d_in[4];
    const float* k_w     = (const float*)d_in[5];
    const float* k_b     = (const float*)d_in[6];
    const float* v_w     = (const float*)d_in[7];
    const float* v_b     = (const float*)d_in[8];
    const float* ln_g    = (const float*)d_in[9];
    const float* ln_b    = (const float*)d_in[10];
    const float* fc_w    = (const float*)d_in[11];
    const float* fc_b    = (const float*)d_in[12];
    float* out = (float*)d_out;
    float* ws  = (float*)d_ws;

    ac_prep_kernel<<<1, 64, 0, stream>>>(embed_w, embed_b, q_w, q_b, k_w, k_b,
                                         v_w, v_b, ln_g, ws);
    ac_prepF_kernel<<<16, 256, 0, stream>>>(fc_w, ln_b, ws);
    ac_autocorr_kernel<<<dim3(BQ, 9), 256, 0, stream>>>(x, ws);
    ac_top2_kernel<<<BQ, 256, 0, stream>>>(ws);
    ac_final_kernel<<<BQ, 256, 0, stream>>>(x, fc_b, ws, out);
}

// Round 2
// 128.353 us; speedup vs baseline: 1.2543x; 1.2543x over previous
//
#include <hip/hip_runtime.h>
#include <math.h>

#define LQ 4096
#define DQ 64
#define BQ 32
#define KSQ 25
#define PADQ 12
#define LN_EPS 1e-5f

#define NT 8            // t-chunks for autocorr
#define TCH (LQ / NT)   // 512

// ws layout (floats):
// [0] alpha, [1] beta, [2] gamma
// [3..8] Mxx, Mss, Mcc, Mxs, Mxc, Msc
// [16..79] u, [80..143] v, [144..207] w
// [256 .. 256+4*4096)        Fu, Fv, Fw, FB
// [16640 .. 16640+32*4)      per-b: lag0, lag1, w0, w1
// [16768 .. +NT*32*2048)     R partials [z][b][lag]
#define WS_U    16
#define WS_V    80
#define WS_W    144
#define WS_F    256
#define WS_TOP  (WS_F + 4 * LQ)
#define WS_PART (WS_TOP + BQ * 4)

__device__ __forceinline__ float wave_sum64(float v) {
    for (int o = 32; o > 0; o >>= 1) v += __shfl_xor(v, o, 64);
    return v;
}

// ---------------- kernel 1: weight-derived scalars/vectors (1 block, 64 thr)
__global__ void ac_prep_kernel(const float* __restrict__ embed_w,
                               const float* __restrict__ embed_b,
                               const float* __restrict__ q_w, const float* __restrict__ q_b,
                               const float* __restrict__ k_w, const float* __restrict__ k_b,
                               const float* __restrict__ v_w, const float* __restrict__ v_b,
                               const float* __restrict__ ln_g,
                               float* __restrict__ ws) {
    int d = threadIdx.x; // 0..63
    float Aq = 0.f, Cq = 0.f, Ak = 0.f, Ck = 0.f, Av = 0.f, Cv = 0.f;
#pragma unroll 8
    for (int e = 0; e < DQ; ++e) {
        float we = embed_w[e], be = embed_b[e];
        float qw = q_w[e * DQ + d], kw = k_w[e * DQ + d], vw = v_w[e * DQ + d];
        Aq = fmaf(we, qw, Aq); Cq = fmaf(be, qw, Cq);
        Ak = fmaf(we, kw, Ak); Ck = fmaf(be, kw, Ck);
        Av = fmaf(we, vw, Av); Cv = fmaf(be, vw, Cv);
    }
    Cq += q_b[d]; Ck += k_b[d]; Cv += v_b[d];

    // z = x*cx + xs*cs + cc
    float cx = embed_w[d];
    float cs = Av;
    float cc = embed_b[d] + Cv;

    const float invD = 1.f / (float)DQ;
    float mx = wave_sum64(cx) * invD;
    float ms = wave_sum64(cs) * invD;
    float mc = wave_sum64(cc) * invD;
    float cxp = cx - mx, csp = cs - ms, ccp = cc - mc;

    float Mxx = wave_sum64(cxp * cxp) * invD;
    float Mss = wave_sum64(csp * csp) * invD;
    float Mcc = wave_sum64(ccp * ccp) * invD;
    float Mxs = wave_sum64(cxp * csp) * invD;
    float Mxc = wave_sum64(cxp * ccp) * invD;
    float Msc = wave_sum64(csp * ccp) * invD;

    float alpha = wave_sum64(Aq * Ak) * invD;
    float beta  = wave_sum64(Aq * Ck + Ak * Cq) * invD;
    float gamma = wave_sum64(Cq * Ck) * ((float)LQ * invD);

    float g = ln_g[d];
    ws[WS_U + d] = cxp * g;
    ws[WS_V + d] = csp * g;
    ws[WS_W + d] = ccp * g;
    if (d == 0) {
        ws[0] = alpha; ws[1] = beta; ws[2] = gamma;
        ws[3] = Mxx; ws[4] = Mss; ws[5] = Mcc;
        ws[6] = Mxs; ws[7] = Mxc; ws[8] = Msc;
    }
}

// ---------------- kernel 2: F arrays (grid 16 x 256)
__global__ void ac_prepF_kernel(const float* __restrict__ fc_w,
                                const float* __restrict__ ln_b,
                                float* __restrict__ ws) {
    __shared__ float su[DQ], sv[DQ], sw[DQ], sb[DQ];
    if (threadIdx.x < DQ) {
        su[threadIdx.x] = ws[WS_U + threadIdx.x];
        sv[threadIdx.x] = ws[WS_V + threadIdx.x];
        sw[threadIdx.x] = ws[WS_W + threadIdx.x];
        sb[threadIdx.x] = ln_b[threadIdx.x];
    }
    __syncthreads();
    int l = blockIdx.x * 256 + threadIdx.x;
    const float4* fc = (const float4*)(fc_w + (size_t)l * DQ);
    float fu = 0.f, fv = 0.f, fw = 0.f, fb = 0.f;
#pragma unroll
    for (int d4 = 0; d4 < DQ / 4; ++d4) {
        float4 f = fc[d4];
        int d = d4 * 4;
        fu = fmaf(su[d], f.x, fu); fu = fmaf(su[d+1], f.y, fu); fu = fmaf(su[d+2], f.z, fu); fu = fmaf(su[d+3], f.w, fu);
        fv = fmaf(sv[d], f.x, fv); fv = fmaf(sv[d+1], f.y, fv); fv = fmaf(sv[d+2], f.z, fv); fv = fmaf(sv[d+3], f.w, fv);
        fw = fmaf(sw[d], f.x, fw); fw = fmaf(sw[d+1], f.y, fw); fw = fmaf(sw[d+2], f.z, fw); fw = fmaf(sw[d+3], f.w, fw);
        fb = fmaf(sb[d], f.x, fb); fb = fmaf(sb[d+1], f.y, fb); fb = fmaf(sb[d+2], f.z, fb); fb = fmaf(sb[d+3], f.w, fb);
    }
    ws[WS_F + l]          = fu;
    ws[WS_F + LQ + l]     = fv;
    ws[WS_F + 2 * LQ + l] = fw;
    ws[WS_F + 3 * LQ + l] = fb;
}

// ---------------- kernel 3: circular autocorrelation partials
// grid (B, 2, NT), 256 thr. Block (b,y,z): lags [y*1024, y*1024+1024),
// t in [z*TCH, z*TCH+TCH). Thread handles 4 consecutive lags via a sliding
// float4 window: per 16 FMA = 1 lane ds_read_b128 + 1 broadcast ds_read_b128.
__global__ void ac_autocorr_kernel(const float* __restrict__ x,
                                   float* __restrict__ ws) {
    __shared__ float sA[TCH];        // x[t0 .. t0+TCH)
    __shared__ float sB[TCH + 1024]; // x[(t0 - lagbase - 1023 + j) mod L]
    int b = blockIdx.x;
    int lagbase = blockIdx.y << 10;
    int t0 = blockIdx.z * TCH;
    const float* xb = x + (size_t)b * LQ;
    int tid = threadIdx.x;

    for (int i = tid; i < TCH; i += 256) sA[i] = xb[t0 + i];
    int start = t0 - lagbase - 1023;            // >= -2047
    for (int j = tid; j < TCH + 1024; j += 256)
        sB[j] = xb[(start + j + LQ) & (LQ - 1)];
    __syncthreads();

    const float4* sA4 = (const float4*)sA;
    const float4* sB4 = (const float4*)sB;
    int base = 255 - tid;
    float4 w0 = sB4[base];
    float a0 = 0.f, a1 = 0.f, a2 = 0.f, a3 = 0.f;
#pragma unroll 4
    for (int c = 0; c < TCH / 4; ++c) {
        float4 w1 = sB4[base + c + 1];
        float4 xa = sA4[c];                     // uniform -> LDS broadcast
        a0 = fmaf(xa.x, w0.w, a0); a1 = fmaf(xa.x, w0.z, a1); a2 = fmaf(xa.x, w0.y, a2); a3 = fmaf(xa.x, w0.x, a3);
        a0 = fmaf(xa.y, w1.x, a0); a1 = fmaf(xa.y, w0.w, a1); a2 = fmaf(xa.y, w0.z, a2); a3 = fmaf(xa.y, w0.y, a3);
        a0 = fmaf(xa.z, w1.y, a0); a1 = fmaf(xa.z, w1.x, a1); a2 = fmaf(xa.z, w0.w, a2); a3 = fmaf(xa.z, w0.z, a3);
        a0 = fmaf(xa.w, w1.z, a0); a1 = fmaf(xa.w, w1.y, a1); a2 = fmaf(xa.w, w1.x, a2); a3 = fmaf(xa.w, w0.w, a3);
        w0 = w1;
    }
    // lag(k) = lagbase + 4*tid + k; acc_k = sum over this t-chunk
    float4* part4 = (float4*)(ws + WS_PART);
    part4[((size_t)(blockIdx.z * BQ + b) * 512) + (blockIdx.y * 256) + tid] =
        make_float4(a0, a1, a2, a3);
}

// ---------------- kernel 4: reduce partials + top-2 + softmax (grid B, 256 thr)
__device__ __forceinline__ bool ac_better(float v, int i, float v2, int i2) {
    return (v > v2) || (v == v2 && i < i2);
}
__global__ void ac_top2_kernel(const float* __restrict__ x,
                               float* __restrict__ ws) {
    __shared__ float sred[256], rred[256];
    __shared__ float sv0[256], sv1[256];
    __shared__ int   si0[256], si1[256];
    int b = blockIdx.x;
    int tid = threadIdx.x;
    const float* xb = x + (size_t)b * LQ;

    // Sx and R[2048]
    float sx = 0.f, r2k = 0.f;
    for (int t = tid; t < LQ; t += 256) {
        float v = xb[t];
        sx  += v;
        r2k += v * xb[(t + 2048) & (LQ - 1)];
    }
    sred[tid] = sx; rred[tid] = r2k;
    __syncthreads();
    for (int st = 128; st > 0; st >>= 1) {
        if (tid < st) { sred[tid] += sred[tid + st]; rred[tid] += rred[tid + st]; }
        __syncthreads();
    }
    float Sx = sred[0], R2048 = rred[0];
    float alpha = ws[0], beta = ws[1], gamma = ws[2];
    float cbase = fmaf(beta, Sx, gamma);

    float v0 = -3.0e38f, v1 = -3.0e38f;
    int i0 = 1 << 30, i1 = 1 << 30;
    const float* part = ws + WS_PART;
    for (int lag = tid; lag < 2048; lag += 256) {
        float R = 0.f;
#pragma unroll
        for (int z = 0; z < NT; ++z)
            R += part[((size_t)(z * BQ + b) * 2048) + lag];
        float v = fmaf(alpha, R, cbase);
        if (ac_better(v, lag, v0, i0)) { v1 = v0; i1 = i0; v0 = v; i0 = lag; }
        else if (ac_better(v, lag, v1, i1)) { v1 = v; i1 = lag; }
        int mir = (LQ - lag) & (LQ - 1);
        if (mir != lag) {
            if (ac_better(v, mir, v0, i0)) { v1 = v0; i1 = i0; v0 = v; i0 = mir; }
            else if (ac_better(v, mir, v1, i1)) { v1 = v; i1 = mir; }
        }
    }
    if (tid == 0) {
        float v = fmaf(alpha, R2048, cbase);
        if (ac_better(v, 2048, v0, i0)) { v1 = v0; i1 = i0; v0 = v; i0 = 2048; }
        else if (ac_better(v, 2048, v1, i1)) { v1 = v; i1 = 2048; }
    }
    sv0[tid] = v0; sv1[tid] = v1; si0[tid] = i0; si1[tid] = i1;
    __syncthreads();
    for (int st = 128; st > 0; st >>= 1) {
        if (tid < st) {
            float a0 = sv0[tid], a1 = sv1[tid];
            int   c0 = si0[tid], c1 = si1[tid];
            float u0 = sv0[tid + st], u1 = sv1[tid + st];
            int   j0 = si0[tid + st], j1 = si1[tid + st];
            float t0v, t1v; int t0i, t1i;
            if (ac_better(a0, c0, u0, j0)) {
                t0v = a0; t0i = c0;
                if (ac_better(u0, j0, a1, c1)) { t1v = u0; t1i = j0; } else { t1v = a1; t1i = c1; }
            } else {
                t0v = u0; t0i = j0;
                if (ac_better(a0, c0, u1, j1)) { t1v = a0; t1i = c0; } else { t1v = u1; t1i = j1; }
            }
            sv0[tid] = t0v; si0[tid] = t0i;
            sv1[tid] = t1v; si1[tid] = t1i;
        }
        __syncthreads();
    }
    if (tid == 0) {
        float w0 = 1.f / (1.f + expf(sv1[0] - sv0[0]));
        float* top = ws + WS_TOP + b * 4;
        top[0] = (float)si0[0]; top[1] = (float)si1[0];
        top[2] = w0; top[3] = 1.f - w0;
    }
}

// ---------------- kernel 5: LN scalars + moving-avg + FC reduce (grid B, 1024 thr)
__global__ void ac_final_kernel(const float* __restrict__ x,
                                const float* __restrict__ fc_b,
                                const float* __restrict__ ws,
                                float* __restrict__ out) {
    __shared__ float pL[LQ], qL[LQ], rL[LQ];
    __shared__ float wred[16];
    int b = blockIdx.x;
    int tid = threadIdx.x;
    const float* xb = x + (size_t)b * LQ;
    const float* top = ws + WS_TOP + b * 4;
    int lag0 = (int)top[0], lag1 = (int)top[1];
    float w0 = top[2], w1 = top[3];
    float Mxx = ws[3], Mss = ws[4], Mcc = ws[5], Mxs = ws[6], Mxc = ws[7], Msc = ws[8];

    for (int l = tid; l < LQ; l += 1024) {
        float xv = xb[l];
        float xs = w0 * xb[(l - lag0) & (LQ - 1)] + w1 * xb[(l - lag1) & (LQ - 1)];
        float var = xv * xv * Mxx + xs * xs * Mss + Mcc
                  + 2.f * xv * xs * Mxs + 2.f * xv * Mxc + 2.f * xs * Msc;
        float r = rsqrtf(var + LN_EPS);
        pL[l] = xv * r; qL[l] = xs * r; rL[l] = r;
    }
    __syncthreads();

    const float* Fu = ws + WS_F;
    const float* Fv = Fu + LQ;
    const float* Fw = Fv + LQ;
    const float* FB = Fw + LQ;
    const float inv = 1.f / (float)KSQ;
    float acc = 0.f;
    for (int l = tid; l < LQ; l += 1024) {
        int lo = l - PADQ; if (lo < 0) lo = 0;
        int hi = l + PADQ; if (hi > LQ - 1) hi = LQ - 1;
        float sp = 0.f, sq = 0.f, sr = 0.f;
        for (int j = lo; j <= hi; ++j) { sp += pL[j]; sq += qL[j]; sr += rL[j]; }
        float cnt = (float)(hi - lo + 1);
        acc += (pL[l] - sp * inv) * Fu[l]
             + (qL[l] - sq * inv) * Fv[l]
             + (rL[l] - sr * inv) * Fw[l]
             + (1.f - cnt * inv) * FB[l];
    }
    acc = wave_sum64(acc);
    int wid = tid >> 6;
    if ((tid & 63) == 0) wred[wid] = acc;
    __syncthreads();
    if (tid == 0) {
        float s = 0.f;
#pragma unroll
        for (int w = 0; w < 16; ++w) s += wred[w];
        out[b] = s + fc_b[0];
    }
}

extern "C" void kernel_launch(void* const* d_in, const int* in_sizes, int n_in,
                              void* d_out, int out_size, void* d_ws, size_t ws_size,
                              hipStream_t stream) {
    const float* x       = (const float*)d_in[0];
    const float* embed_w = (const float*)d_in[1];
    const float* embed_b = (const float*)d_in[2];
    const float* q_w     = (const float*)d_in[3];
    const float* q_b     = (const float*)d_in[4];
    const float* k_w     = (const float*)d_in[5];
    const float* k_b     = (const float*)d_in[6];
    const float* v_w     = (const float*)d_in[7];
    const float* v_b     = (const float*)d_in[8];
    const float* ln_g    = (const float*)d_in[9];
    const float* ln_b    = (const float*)d_in[10];
    const float* fc_w    = (const float*)d_in[11];
    const float* fc_b    = (const float*)d_in[12];
    float* out = (float*)d_out;
    float* ws  = (float*)d_ws;

    ac_prep_kernel<<<1, 64, 0, stream>>>(embed_w, embed_b, q_w, q_b, k_w, k_b,
                                         v_w, v_b, ln_g, ws);
    ac_prepF_kernel<<<16, 256, 0, stream>>>(fc_w, ln_b, ws);
    ac_autocorr_kernel<<<dim3(BQ, 2, NT), 256, 0, stream>>>(x, ws);
    ac_top2_kernel<<<BQ, 256, 0, stream>>>(x, ws);
    ac_final_kernel<<<BQ, 1024, 0, stream>>>(x, fc_b, ws, out);
}

// Round 3
// 116.594 us; speedup vs baseline: 1.3808x; 1.1009x over previous
//
#include <hip/hip_runtime.h>
#include <math.h>

#define LQ 4096
#define DQ 64
#define BQ 32
#define KSQ 25
#define PADQ 12
#define LN_EPS 1e-5f

#define NT 8            // t-chunks for autocorr
#define TCH (LQ / NT)   // 512
#define NAC (BQ * 2 * NT)   // 512 autocorr blocks

// ws layout (floats):
// [0 .. 4*4096)           F'u, F'v, F'w, FB'  (window-adjoint folded)
// [16384 .. +NT*32*2048)  R partials [z][b][lag]
#define WS_PART 16384

__device__ __forceinline__ float wave_sum64(float v) {
    for (int o = 32; o > 0; o >>= 1) v += __shfl_xor(v, o, 64);
    return v;
}

__device__ __forceinline__ bool ac_better(float v, int i, float v2, int i2) {
    return (v > v2) || (v == v2 && i < i2);
}

// ================= kernel 1: autocorr partials (blocks 0..511)
//                 + windowed F' prep      (blocks 512..527)
__global__ void ac_stage1_kernel(const float* __restrict__ x,
                                 const float* __restrict__ fc_w,
                                 const float* __restrict__ ln_g,
                                 const float* __restrict__ ln_b,
                                 const float* __restrict__ embed_w,
                                 const float* __restrict__ embed_b,
                                 const float* __restrict__ v_w,
                                 const float* __restrict__ v_b,
                                 float* __restrict__ ws) {
    __shared__ float smem[2048];
    int tid = threadIdx.x;

    if (blockIdx.x < NAC) {
        // ---------- autocorrelation partials ----------
        float* sA = smem;          // [TCH]
        float* sB = smem + TCH;    // [TCH + 1024]
        int b = blockIdx.x & 31;
        int y = (blockIdx.x >> 5) & 1;
        int z = blockIdx.x >> 6;
        int lagbase = y << 10;
        int t0 = z * TCH;
        const float* xb = x + (size_t)b * LQ;

        for (int i = tid; i < TCH; i += 256) sA[i] = xb[t0 + i];
        int start = t0 - lagbase - 1023;
        for (int j = tid; j < TCH + 1024; j += 256)
            sB[j] = xb[(start + j + LQ) & (LQ - 1)];
        __syncthreads();

        const float4* sA4 = (const float4*)sA;
        const float4* sB4 = (const float4*)sB;
        int base = 255 - tid;
        float4 w0 = sB4[base];
        float a0 = 0.f, a1 = 0.f, a2 = 0.f, a3 = 0.f;
#pragma unroll 4
        for (int c = 0; c < TCH / 4; ++c) {
            float4 w1 = sB4[base + c + 1];
            float4 xa = sA4[c];                 // uniform -> LDS broadcast
            a0 = fmaf(xa.x, w0.w, a0); a1 = fmaf(xa.x, w0.z, a1); a2 = fmaf(xa.x, w0.y, a2); a3 = fmaf(xa.x, w0.x, a3);
            a0 = fmaf(xa.y, w1.x, a0); a1 = fmaf(xa.y, w0.w, a1); a2 = fmaf(xa.y, w0.z, a2); a3 = fmaf(xa.y, w0.y, a3);
            a0 = fmaf(xa.z, w1.y, a0); a1 = fmaf(xa.z, w1.x, a1); a2 = fmaf(xa.z, w0.w, a2); a3 = fmaf(xa.z, w0.z, a3);
            a0 = fmaf(xa.w, w1.z, a0); a1 = fmaf(xa.w, w1.y, a1); a2 = fmaf(xa.w, w1.x, a2); a3 = fmaf(xa.w, w0.w, a3);
            w0 = w1;
        }
        float4* part4 = (float4*)(ws + WS_PART);
        part4[((size_t)(z * BQ + b) * 512) + (y * 256) + tid] =
            make_float4(a0, a1, a2, a3);
    } else {
        // ---------- windowed F' prep ----------
        float* Hu = smem;            // [280]
        float* Hv = smem + 280;
        float* Hw = smem + 560;
        float* Hb = smem + 840;
        float* su = smem + 1120;     // [64]
        float* sv = smem + 1184;
        float* sw = smem + 1248;
        float* sb = smem + 1312;

        if (tid < DQ) {
            int d = tid;
            float Av = 0.f, Cv = 0.f;
#pragma unroll 8
            for (int e = 0; e < DQ; ++e) {
                float vw = v_w[e * DQ + d];
                Av = fmaf(embed_w[e], vw, Av);
                Cv = fmaf(embed_b[e], vw, Cv);
            }
            Cv += v_b[d];
            float cx = embed_w[d];
            float cs = Av;
            float cc = embed_b[d] + Cv;
            const float invD = 1.f / (float)DQ;
            float mx = wave_sum64(cx) * invD;
            float ms = wave_sum64(cs) * invD;
            float mc = wave_sum64(cc) * invD;
            float g = ln_g[d];
            su[d] = (cx - mx) * g;
            sv[d] = (cs - ms) * g;
            sw[d] = (cc - mc) * g;
            sb[d] = ln_b[d];
        }
        __syncthreads();

        int lbase = (blockIdx.x - NAC) * 256;
        for (int i = tid; i < 256 + 2 * PADQ; i += 256) {
            int l = lbase - PADQ + i;
            float fu = 0.f, fv = 0.f, fw = 0.f, fb = 0.f;
            if (l >= 0 && l < LQ) {
                const float4* fc = (const float4*)(fc_w + (size_t)l * DQ);
#pragma unroll
                for (int d4 = 0; d4 < DQ / 4; ++d4) {
                    float4 f = fc[d4];
                    int d = d4 * 4;
                    fu = fmaf(su[d], f.x, fu); fu = fmaf(su[d+1], f.y, fu); fu = fmaf(su[d+2], f.z, fu); fu = fmaf(su[d+3], f.w, fu);
                    fv = fmaf(sv[d], f.x, fv); fv = fmaf(sv[d+1], f.y, fv); fv = fmaf(sv[d+2], f.z, fv); fv = fmaf(sv[d+3], f.w, fv);
                    fw = fmaf(sw[d], f.x, fw); fw = fmaf(sw[d+1], f.y, fw); fw = fmaf(sw[d+2], f.z, fw); fw = fmaf(sw[d+3], f.w, fw);
                    fb = fmaf(sb[d], f.x, fb); fb = fmaf(sb[d+1], f.y, fb); fb = fmaf(sb[d+2], f.z, fb); fb = fmaf(sb[d+3], f.w, fb);
                }
            }
            Hu[i] = fu; Hv[i] = fv; Hw[i] = fw; Hb[i] = fb;
        }
        __syncthreads();

        int l = lbase + tid;
        int i = tid + PADQ;
        float Gu = 0.f, Gv = 0.f, Gw = 0.f;
#pragma unroll
        for (int k = -PADQ; k <= PADQ; ++k) {
            Gu += Hu[i + k]; Gv += Hv[i + k]; Gw += Hw[i + k];
        }
        int lo = l - PADQ; if (lo < 0) lo = 0;
        int hi = l + PADQ; if (hi > LQ - 1) hi = LQ - 1;
        const float inv = 1.f / (float)KSQ;
        float cnt = (float)(hi - lo + 1);
        ws[l]          = Hu[i] - Gu * inv;
        ws[LQ + l]     = Hv[i] - Gv * inv;
        ws[2 * LQ + l] = Hw[i] - Gw * inv;
        ws[3 * LQ + l] = (1.f - cnt * inv) * Hb[i];
    }
}

// ================= kernel 2: per-b scalars + top2 + fused LN/FC (grid B, 1024 thr)
__global__ void __launch_bounds__(1024)
ac_final_kernel(const float* __restrict__ x,
                const float* __restrict__ embed_w, const float* __restrict__ embed_b,
                const float* __restrict__ q_w, const float* __restrict__ q_b,
                const float* __restrict__ k_w, const float* __restrict__ k_b,
                const float* __restrict__ v_w, const float* __restrict__ v_b,
                const float* __restrict__ fc_b,
                const float* __restrict__ ws,
                float* __restrict__ out) {
    __shared__ float4 xs4_[LQ / 4];
    __shared__ float scal[16];
    __shared__ float red[32];
    __shared__ float tv0[16], tv1[16];
    __shared__ int   ti0[16], ti1[16];
    float* xs_ = (float*)xs4_;

    int b = blockIdx.x;
    int tid = threadIdx.x;
    int wv = tid >> 6;
    const float* xb = x + (size_t)b * LQ;

    // stage x (one float4 per thread)
    xs4_[tid] = ((const float4*)xb)[tid];

    // wave 0: weight-derived scalars (independent of x)
    if (tid < DQ) {
        int d = tid;
        float Aq = 0.f, Cq = 0.f, Ak = 0.f, Ck = 0.f, Av = 0.f, Cv = 0.f;
#pragma unroll 8
        for (int e = 0; e < DQ; ++e) {
            float we = embed_w[e], be = embed_b[e];
            float qw = q_w[e * DQ + d], kw = k_w[e * DQ + d], vw = v_w[e * DQ + d];
            Aq = fmaf(we, qw, Aq); Cq = fmaf(be, qw, Cq);
            Ak = fmaf(we, kw, Ak); Ck = fmaf(be, kw, Ck);
            Av = fmaf(we, vw, Av); Cv = fmaf(be, vw, Cv);
        }
        Cq += q_b[d]; Ck += k_b[d]; Cv += v_b[d];
        float cx = embed_w[d];
        float cs = Av;
        float cc = embed_b[d] + Cv;
        const float invD = 1.f / (float)DQ;
        float mx = wave_sum64(cx) * invD;
        float ms = wave_sum64(cs) * invD;
        float mc = wave_sum64(cc) * invD;
        float cxp = cx - mx, csp = cs - ms, ccp = cc - mc;
        float Mxx = wave_sum64(cxp * cxp) * invD;
        float Mss = wave_sum64(csp * csp) * invD;
        float Mcc = wave_sum64(ccp * ccp) * invD;
        float Mxs = wave_sum64(cxp * csp) * invD;
        float Mxc = wave_sum64(cxp * ccp) * invD;
        float Msc = wave_sum64(csp * ccp) * invD;
        float alpha = wave_sum64(Aq * Ak) * invD;
        float beta  = wave_sum64(Aq * Ck + Ak * Cq) * invD;
        float gamma = wave_sum64(Cq * Ck) * ((float)LQ * invD);
        if (d == 0) {
            scal[2] = alpha; scal[3] = beta; scal[4] = gamma;
            scal[5] = Mxx; scal[6] = Mss; scal[7] = Mcc;
            scal[8] = Mxs; scal[9] = Mxc; scal[10] = Msc;
        }
    }
    __syncthreads();

    // Sx and R[2048] from LDS
    {
        float sx = 0.f, r2k = 0.f;
#pragma unroll
        for (int k = 0; k < 4; ++k) {
            int t = tid + k * 1024;
            float v = xs_[t];
            sx  += v;
            r2k += v * xs_[(t + 2048) & (LQ - 1)];
        }
        sx  = wave_sum64(sx);
        r2k = wave_sum64(r2k);
        if ((tid & 63) == 0) { red[wv] = sx; red[16 + wv] = r2k; }
    }
    __syncthreads();
    if (tid == 0) {
        float sx = 0.f, r2k = 0.f;
#pragma unroll
        for (int w = 0; w < 16; ++w) { sx += red[w]; r2k += red[16 + w]; }
        scal[0] = sx; scal[1] = r2k;
        scal[11] = fmaf(scal[3], sx, scal[4]);   // cbase
    }
    __syncthreads();

    // top-2 over lags (each thread: 2 lags + mirrors)
    {
        float alpha = scal[2], cbase = scal[11];
        float v0 = -3.0e38f, v1 = -3.0e38f;
        int i0 = 1 << 30, i1 = 1 << 30;
        const float* part = ws + WS_PART;
#pragma unroll
        for (int k = 0; k < 2; ++k) {
            int lag = tid + k * 1024;
            float R = 0.f;
#pragma unroll
            for (int z = 0; z < NT; ++z)
                R += part[((size_t)(z * BQ + b) * 2048) + lag];
            float v = fmaf(alpha, R, cbase);
            if (ac_better(v, lag, v0, i0)) { v1 = v0; i1 = i0; v0 = v; i0 = lag; }
            else if (ac_better(v, lag, v1, i1)) { v1 = v; i1 = lag; }
            int mir = (LQ - lag) & (LQ - 1);
            if (mir != lag) {
                if (ac_better(v, mir, v0, i0)) { v1 = v0; i1 = i0; v0 = v; i0 = mir; }
                else if (ac_better(v, mir, v1, i1)) { v1 = v; i1 = mir; }
            }
        }
        // wave-level top2 merge
        for (int o = 32; o > 0; o >>= 1) {
            float u0 = __shfl_xor(v0, o, 64); int j0 = __shfl_xor(i0, o, 64);
            float u1 = __shfl_xor(v1, o, 64); int j1 = __shfl_xor(i1, o, 64);
            if (ac_better(u0, j0, v0, i0)) {
                if (ac_better(v0, i0, u1, j1)) { v1 = v0; i1 = i0; }
                else                           { v1 = u1; i1 = j1; }
                v0 = u0; i0 = j0;
            } else if (ac_better(u0, j0, v1, i1)) { v1 = u0; i1 = j0; }
        }
        if ((tid & 63) == 0) { tv0[wv] = v0; ti0[wv] = i0; tv1[wv] = v1; ti1[wv] = i1; }
    }
    __syncthreads();
    if (tid == 0) {
        float v0 = tv0[0], v1 = tv1[0];
        int i0 = ti0[0], i1 = ti1[0];
#pragma unroll
        for (int w = 1; w < 16; ++w) {
            float u0 = tv0[w], u1 = tv1[w];
            int j0 = ti0[w], j1 = ti1[w];
            if (ac_better(u0, j0, v0, i0)) {
                if (ac_better(v0, i0, u1, j1)) { v1 = v0; i1 = i0; }
                else                           { v1 = u1; i1 = j1; }
                v0 = u0; i0 = j0;
            } else if (ac_better(u0, j0, v1, i1)) { v1 = u0; i1 = j0; }
        }
        // lag 2048 candidate
        float v2k = fmaf(scal[2], scal[1], scal[11]);
        if (ac_better(v2k, 2048, v0, i0)) {
            if (ac_better(v0, i0, v1, i1)) { v1 = v0; i1 = i0; }
            v0 = v2k; i0 = 2048;
        } else if (ac_better(v2k, 2048, v1, i1)) { v1 = v2k; i1 = 2048; }
        float w0 = 1.f / (1.f + expf(v1 - v0));
        scal[12] = (float)i0; scal[13] = (float)i1;
        scal[14] = w0; scal[15] = 1.f - w0;
    }
    __syncthreads();

    // fused LN + (pre-windowed) FC reduce
    {
        int lag0 = (int)scal[12], lag1 = (int)scal[13];
        float w0 = scal[14], w1 = scal[15];
        float Mxx = scal[5], Mss = scal[6], Mcc = scal[7];
        float Mxs = scal[8], Mxc = scal[9], Msc = scal[10];
        const float* Fpu = ws;
        const float* Fpv = ws + LQ;
        const float* Fpw = ws + 2 * LQ;
        const float* FBp = ws + 3 * LQ;
        float acc = 0.f;
#pragma unroll
        for (int k = 0; k < 4; ++k) {
            int l = tid + k * 1024;
            float xv = xs_[l];
            float xsv = w0 * xs_[(l - lag0) & (LQ - 1)] + w1 * xs_[(l - lag1) & (LQ - 1)];
            float var = xv * xv * Mxx + xsv * xsv * Mss + Mcc
                      + 2.f * xv * xsv * Mxs + 2.f * xv * Mxc + 2.f * xsv * Msc;
            float r = rsqrtf(var + LN_EPS);
            acc += (xv * r) * Fpu[l] + (xsv * r) * Fpv[l] + r * Fpw[l] + FBp[l];
        }
        acc = wave_sum64(acc);
        if ((tid & 63) == 0) red[wv] = acc;
    }
    __syncthreads();
    if (tid == 0) {
        float s = 0.f;
#pragma unroll
        for (int w = 0; w < 16; ++w) s += red[w];
        out[b] = s + fc_b[0];
    }
}

extern "C" void kernel_launch(void* const* d_in, const int* in_sizes, int n_in,
                              void* d_out, int out_size, void* d_ws, size_t ws_size,
                              hipStream_t stream) {
    const float* x       = (const float*)d_in[0];
    const float* embed_w = (const float*)d_in[1];
    const float* embed_b = (const float*)d_in[2];
    const float* q_w     = (const float*)d_in[3];
    const float* q_b     = (const float*)d_in[4];
    const float* k_w     = (const float*)d_in[5];
    const float* k_b     = (const float*)d_in[6];
    const float* v_w     = (const float*)d_in[7];
    const float* v_b     = (const float*)d_in[8];
    const float* ln_g    = (const float*)d_in[9];
    const float* ln_b    = (const float*)d_in[10];
    const float* fc_w    = (const float*)d_in[11];
    const float* fc_b    = (const float*)d_in[12];
    float* out = (float*)d_out;
    float* ws  = (float*)d_ws;

    ac_stage1_kernel<<<NAC + 16, 256, 0, stream>>>(x, fc_w, ln_g, ln_b,
                                                   embed_w, embed_b, v_w, v_b, ws);
    ac_final_kernel<<<BQ, 1024, 0, stream>>>(x, embed_w, embed_b, q_w, q_b,
                                             k_w, k_b, v_w, v_b, fc_b, ws, out);
}

// Round 5
// 111.135 us; speedup vs baseline: 1.4487x; 1.0491x over previous
//
#include <hip/hip_runtime.h>
#include <math.h>

#define LQ 4096
#define DQ 64
#define BQ 32
#define KSQ 25
#define PADQ 12
#define LN_EPS 1e-5f

#define NT 8              // t-chunks for autocorr
#define TCH (LQ / NT)     // 512
#define NAC (BQ * NT)     // 256 autocorr blocks (each: all 2048 lags, one t-chunk)
#define NFP 16            // F' prep blocks
#define NPB 16            // per-b Sx/R2048 blocks
#define NBLK (NAC + NFP + NPB) // 288

// ws layout (floats):
// [0 .. 4*4096)            F'u, F'v, F'w, FB'  (window-adjoint folded)
// [16384 .. +NT*32*2048)   R partials [z][b][lag]
// [WS_SCAL .. +16)         alpha,beta,gamma,Mxx,Mss,Mcc,Mxs,Mxc,Msc
// [WS_SB .. +64)           Sx[32], R2048[32]
#define WS_PART 16384
#define WS_SCAL (WS_PART + NT * BQ * 2048)
#define WS_SB   (WS_SCAL + 16)

__device__ __forceinline__ float wave_sum64(float v) {
    for (int o = 32; o > 0; o >>= 1) v += __shfl_xor(v, o, 64);
    return v;
}

__device__ __forceinline__ bool ac_better(float v, int i, float v2, int i2) {
    return (v > v2) || (v == v2 && i < i2);
}

__device__ __forceinline__ void top2_upd(float v, int i,
                                         float& v0, int& i0, float& v1, int& i1) {
    if (ac_better(v, i, v0, i0)) { v1 = v0; i1 = i0; v0 = v; i0 = i; }
    else if (ac_better(v, i, v1, i1)) { v1 = v; i1 = i; }
}

// ================= kernel 1: autocorr partials (blocks 0..255)
//                 + windowed F' prep (256..271) + per-b Sx/R2048 (+scal) (272..287)
__global__ void __launch_bounds__(256)
ac_stage1_kernel(const float* __restrict__ x,
                 const float* __restrict__ fc_w,
                 const float* __restrict__ ln_g, const float* __restrict__ ln_b,
                 const float* __restrict__ embed_w, const float* __restrict__ embed_b,
                 const float* __restrict__ q_w, const float* __restrict__ q_b,
                 const float* __restrict__ k_w, const float* __restrict__ k_b,
                 const float* __restrict__ v_w, const float* __restrict__ v_b,
                 float* __restrict__ ws) {
    __shared__ float smem[3072];   // 12 KB
    int tid = threadIdx.x;
    int blk = blockIdx.x;

    if (blk < NAC) {
        // ---------- autocorrelation partials: 8 lags/thread sliding window ----
        // R_partial[lag] = sum_{t in chunk} x[t]*x[(t-lag) mod L], lag in [0,2048)
        float* sA = smem;          // [TCH]        x[t0 .. t0+TCH)
        float* sB = smem + TCH;    // [TCH+2048]   x[(t0-2047+j) mod L]
        int b = blk & 31;
        int z = blk >> 5;
        int t0 = z * TCH;
        const float* xb = x + (size_t)b * LQ;

        for (int i = tid; i < TCH; i += 256) sA[i] = xb[t0 + i];
        int start = t0 - 2047;
        for (int j = tid; j < TCH + 2048; j += 256)
            sB[j] = xb[(start + j + LQ) & (LQ - 1)];
        __syncthreads();

        const float4* sA4 = (const float4*)sA;
        const float4* sB4 = (const float4*)sB;
        // thread handles lags [8*tid, 8*tid+8). partner pos for (c,r):
        //   c + 2047 - 8*tid - r  ->  W[k+7-r] at Wbase = 4*c4 + 2040 - 8*tid
        int B0 = 510 - 2 * tid;    // float4 index of W base at c4=0
        float4 w0 = sB4[B0];
        float4 w1 = sB4[B0 + 1];
        float a0 = 0.f, a1 = 0.f, a2 = 0.f, a3 = 0.f;
        float a4 = 0.f, a5 = 0.f, a6 = 0.f, a7 = 0.f;
#pragma unroll 4
        for (int c4 = 0; c4 < TCH / 4; ++c4) {
            float4 w2 = sB4[B0 + c4 + 2];
            float4 xa = sA4[c4];               // uniform -> LDS broadcast
            // W0..W10 = w0.xyzw w1.xyzw w2.xyz ; acc_r uses W[k+7-r]
            a7 = fmaf(xa.x, w0.x, a7); a7 = fmaf(xa.y, w0.y, a7); a7 = fmaf(xa.z, w0.z, a7); a7 = fmaf(xa.w, w0.w, a7);
            a6 = fmaf(xa.x, w0.y, a6); a6 = fmaf(xa.y, w0.z, a6); a6 = fmaf(xa.z, w0.w, a6); a6 = fmaf(xa.w, w1.x, a6);
            a5 = fmaf(xa.x, w0.z, a5); a5 = fmaf(xa.y, w0.w, a5); a5 = fmaf(xa.z, w1.x, a5); a5 = fmaf(xa.w, w1.y, a5);
            a4 = fmaf(xa.x, w0.w, a4); a4 = fmaf(xa.y, w1.x, a4); a4 = fmaf(xa.z, w1.y, a4); a4 = fmaf(xa.w, w1.z, a4);
            a3 = fmaf(xa.x, w1.x, a3); a3 = fmaf(xa.y, w1.y, a3); a3 = fmaf(xa.z, w1.z, a3); a3 = fmaf(xa.w, w1.w, a3);
            a2 = fmaf(xa.x, w1.y, a2); a2 = fmaf(xa.y, w1.z, a2); a2 = fmaf(xa.z, w1.w, a2); a2 = fmaf(xa.w, w2.x, a2);
            a1 = fmaf(xa.x, w1.z, a1); a1 = fmaf(xa.y, w1.w, a1); a1 = fmaf(xa.z, w2.x, a1); a1 = fmaf(xa.w, w2.y, a1);
            a0 = fmaf(xa.x, w1.w, a0); a0 = fmaf(xa.y, w2.x, a0); a0 = fmaf(xa.z, w2.y, a0); a0 = fmaf(xa.w, w2.z, a0);
            w0 = w1; w1 = w2;
        }
        float4* part4 = (float4*)(ws + WS_PART + (size_t)(z * BQ + b) * 2048);
        part4[2 * tid]     = make_float4(a0, a1, a2, a3);
        part4[2 * tid + 1] = make_float4(a4, a5, a6, a7);
    } else if (blk < NAC + NFP) {
        // ---------- windowed F' prep ----------
        float* Hu = smem;            // [280]
        float* Hv = smem + 280;
        float* Hw = smem + 560;
        float* Hb = smem + 840;
        float* su = smem + 1120;     // [64]
        float* sv = smem + 1184;
        float* sw = smem + 1248;
        float* sb = smem + 1312;

        if (tid < DQ) {
            int d = tid;
            float Av = 0.f, Cv = 0.f;
#pragma unroll 8
            for (int e = 0; e < DQ; ++e) {
                float vw = v_w[e * DQ + d];
                Av = fmaf(embed_w[e], vw, Av);
                Cv = fmaf(embed_b[e], vw, Cv);
            }
            Cv += v_b[d];
            float cx = embed_w[d];
            float cs = Av;
            float cc = embed_b[d] + Cv;
            const float invD = 1.f / (float)DQ;
            float mx = wave_sum64(cx) * invD;
            float ms = wave_sum64(cs) * invD;
            float mc = wave_sum64(cc) * invD;
            float g = ln_g[d];
            su[d] = (cx - mx) * g;
            sv[d] = (cs - ms) * g;
            sw[d] = (cc - mc) * g;
            sb[d] = ln_b[d];
        }
        __syncthreads();

        int lbase = (blk - NAC) * 256;
        for (int i = tid; i < 256 + 2 * PADQ; i += 256) {
            int l = lbase - PADQ + i;
            float fu = 0.f, fv = 0.f, fw = 0.f, fb = 0.f;
            if (l >= 0 && l < LQ) {
                const float4* fc = (const float4*)(fc_w + (size_t)l * DQ);
#pragma unroll
                for (int d4 = 0; d4 < DQ / 4; ++d4) {
                    float4 f = fc[d4];
                    int d = d4 * 4;
                    fu = fmaf(su[d], f.x, fu); fu = fmaf(su[d+1], f.y, fu); fu = fmaf(su[d+2], f.z, fu); fu = fmaf(su[d+3], f.w, fu);
                    fv = fmaf(sv[d], f.x, fv); fv = fmaf(sv[d+1], f.y, fv); fv = fmaf(sv[d+2], f.z, fv); fv = fmaf(sv[d+3], f.w, fv);
                    fw = fmaf(sw[d], f.x, fw); fw = fmaf(sw[d+1], f.y, fw); fw = fmaf(sw[d+2], f.z, fw); fw = fmaf(sw[d+3], f.w, fw);
                    fb = fmaf(sb[d], f.x, fb); fb = fmaf(sb[d+1], f.y, fb); fb = fmaf(sb[d+2], f.z, fb); fb = fmaf(sb[d+3], f.w, fb);
                }
            }
            Hu[i] = fu; Hv[i] = fv; Hw[i] = fw; Hb[i] = fb;
        }
        __syncthreads();

        int l = lbase + tid;
        int i = tid + PADQ;
        float Gu = 0.f, Gv = 0.f, Gw = 0.f;
#pragma unroll
        for (int k = -PADQ; k <= PADQ; ++k) {
            Gu += Hu[i + k]; Gv += Hv[i + k]; Gw += Hw[i + k];
        }
        int lo = l - PADQ; if (lo < 0) lo = 0;
        int hi = l + PADQ; if (hi > LQ - 1) hi = LQ - 1;
        const float inv = 1.f / (float)KSQ;
        float cnt = (float)(hi - lo + 1);
        ws[l]          = Hu[i] - Gu * inv;
        ws[LQ + l]     = Hv[i] - Gv * inv;
        ws[2 * LQ + l] = Hw[i] - Gw * inv;
        ws[3 * LQ + l] = (1.f - cnt * inv) * Hb[i];
    } else {
        // ---------- per-b Sx / R2048 (+ block 0 of this group: weight scalars)
        int i = blk - (NAC + NFP);
#pragma unroll
        for (int bb = 0; bb < 2; ++bb) {
            int b = i * 2 + bb;
            const float* xb = x + (size_t)b * LQ;
            float sx = 0.f, r2k = 0.f;
#pragma unroll
            for (int k = 0; k < LQ / 256; ++k) {
                int t = tid + k * 256;
                float v = xb[t];
                sx  += v;
                r2k += v * xb[(t + 2048) & (LQ - 1)];
            }
            sx  = wave_sum64(sx);
            r2k = wave_sum64(r2k);
            int wv = tid >> 6;
            if ((tid & 63) == 0) { smem[wv] = sx; smem[8 + wv] = r2k; }
            __syncthreads();
            if (tid == 0) {
                ws[WS_SB + b]      = smem[0] + smem[1] + smem[2] + smem[3];
                ws[WS_SB + BQ + b] = smem[8] + smem[9] + smem[10] + smem[11];
            }
            __syncthreads();
        }
        if (i == 0 && tid < DQ) {
            int d = tid;
            float Aq = 0.f, Cq = 0.f, Ak = 0.f, Ck = 0.f, Av = 0.f, Cv = 0.f;
#pragma unroll 8
            for (int e = 0; e < DQ; ++e) {
                float we = embed_w[e], be = embed_b[e];
                float qw = q_w[e * DQ + d], kw = k_w[e * DQ + d], vw = v_w[e * DQ + d];
                Aq = fmaf(we, qw, Aq); Cq = fmaf(be, qw, Cq);
                Ak = fmaf(we, kw, Ak); Ck = fmaf(be, kw, Ck);
                Av = fmaf(we, vw, Av); Cv = fmaf(be, vw, Cv);
            }
            Cq += q_b[d]; Ck += k_b[d]; Cv += v_b[d];
            float cx = embed_w[d];
            float cs = Av;
            float cc = embed_b[d] + Cv;
            const float invD = 1.f / (float)DQ;
            float mx = wave_sum64(cx) * invD;
            float ms = wave_sum64(cs) * invD;
            float mc = wave_sum64(cc) * invD;
            float cxp = cx - mx, csp = cs - ms, ccp = cc - mc;
            float Mxx = wave_sum64(cxp * cxp) * invD;
            float Mss = wave_sum64(csp * csp) * invD;
            float Mcc = wave_sum64(ccp * ccp) * invD;
            float Mxs = wave_sum64(cxp * csp) * invD;
            float Mxc = wave_sum64(cxp * ccp) * invD;
            float Msc = wave_sum64(csp * ccp) * invD;
            float alpha = wave_sum64(Aq * Ak) * invD;
            float beta  = wave_sum64(Aq * Ck + Ak * Cq) * invD;
            float gamma = wave_sum64(Cq * Ck) * ((float)LQ * invD);
            if (d == 0) {
                ws[WS_SCAL + 0] = alpha; ws[WS_SCAL + 1] = beta; ws[WS_SCAL + 2] = gamma;
                ws[WS_SCAL + 3] = Mxx; ws[WS_SCAL + 4] = Mss; ws[WS_SCAL + 5] = Mcc;
                ws[WS_SCAL + 6] = Mxs; ws[WS_SCAL + 7] = Mxc; ws[WS_SCAL + 8] = Msc;
            }
        }
    }
}

// ================= kernel 2: top2 + fused LN/FC (grid B, 1024 thr)
__global__ void __launch_bounds__(1024)
ac_final_kernel(const float* __restrict__ x,
                const float* __restrict__ fc_b,
                const float* __restrict__ ws,
                float* __restrict__ out) {
    __shared__ float4 xs4_[LQ / 4];
    __shared__ float scal[32];
    __shared__ float red[16];
    __shared__ float tv0[16], tv1[16];
    __shared__ int   ti0[16], ti1[16];
    float* xs_ = (float*)xs4_;

    int b = blockIdx.x;
    int tid = threadIdx.x;
    int wv = tid >> 6;
    const float* xb = x + (size_t)b * LQ;

    // stage x (one float4 per thread)
    xs4_[tid] = ((const float4*)xb)[tid];

    float alpha = ws[WS_SCAL + 0], beta = ws[WS_SCAL + 1], gamma = ws[WS_SCAL + 2];
    float Mxx = ws[WS_SCAL + 3], Mss = ws[WS_SCAL + 4], Mcc = ws[WS_SCAL + 5];
    float Mxs = ws[WS_SCAL + 6], Mxc = ws[WS_SCAL + 7], Msc = ws[WS_SCAL + 8];
    float Sxb = ws[WS_SB + b], R2k = ws[WS_SB + BQ + b];
    float cbase = fmaf(beta, Sxb, gamma);

    // top-2 over lags (each thread: 2 lags + mirrors)
    {
        float v0 = -3.0e38f, v1 = -3.0e38f;
        int i0 = 1 << 30, i1 = 1 << 30;
        const float* part = ws + WS_PART;
#pragma unroll
        for (int k = 0; k < 2; ++k) {
            int lag = tid + k * 1024;
            float R = 0.f;
#pragma unroll
            for (int z = 0; z < NT; ++z)
                R += part[((size_t)(z * BQ + b) * 2048) + lag];
            float v = fmaf(alpha, R, cbase);
            top2_upd(v, lag, v0, i0, v1, i1);
            int mir = (LQ - lag) & (LQ - 1);
            if (mir != lag) top2_upd(v, mir, v0, i0, v1, i1);
        }
        // wave-level top2 merge
        for (int o = 32; o > 0; o >>= 1) {
            float u0 = __shfl_xor(v0, o, 64); int j0 = __shfl_xor(i0, o, 64);
            float u1 = __shfl_xor(v1, o, 64); int j1 = __shfl_xor(i1, o, 64);
            if (ac_better(u0, j0, v0, i0)) {
                if (ac_better(v0, i0, u1, j1)) { v1 = v0; i1 = i0; }
                else                           { v1 = u1; i1 = j1; }
                v0 = u0; i0 = j0;
            } else if (ac_better(u0, j0, v1, i1)) { v1 = u0; i1 = j0; }
        }
        if ((tid & 63) == 0) { tv0[wv] = v0; ti0[wv] = i0; tv1[wv] = v1; ti1[wv] = i1; }
    }
    __syncthreads();
    if (tid == 0) {
        float v0 = tv0[0], v1 = tv1[0];
        int i0 = ti0[0], i1 = ti1[0];
#pragma unroll
        for (int w = 1; w < 16; ++w) {
            float u0 = tv0[w], u1 = tv1[w];
            int j0 = ti0[w], j1 = ti1[w];
            if (ac_better(u0, j0, v0, i0)) {
                if (ac_better(v0, i0, u1, j1)) { v1 = v0; i1 = i0; }
                else                           { v1 = u1; i1 = j1; }
                v0 = u0; i0 = j0;
            } else if (ac_better(u0, j0, v1, i1)) { v1 = u0; i1 = j0; }
        }
        float v2k = fmaf(alpha, R2k, cbase);
        if (ac_better(v2k, 2048, v0, i0)) {
            if (ac_better(v0, i0, v1, i1)) { v1 = v0; i1 = i0; }
            v0 = v2k; i0 = 2048;
        } else if (ac_better(v2k, 2048, v1, i1)) { v1 = v2k; i1 = 2048; }
        float w0 = 1.f / (1.f + expf(v1 - v0));
        scal[0] = (float)i0; scal[1] = (float)i1;
        scal[2] = w0; scal[3] = 1.f - w0;
    }
    __syncthreads();

    // fused LN + (pre-windowed) FC reduce
    {
        int lag0 = (int)scal[0], lag1 = (int)scal[1];
        float w0 = scal[2], w1 = scal[3];
        const float* Fpu = ws;
        const float* Fpv = ws + LQ;
        const float* Fpw = ws + 2 * LQ;
        const float* FBp = ws + 3 * LQ;
        float acc = 0.f;
#pragma unroll
        for (int k = 0; k < 4; ++k) {
            int l = tid + k * 1024;
            float xv = xs_[l];
            float xsv = w0 * xs_[(l - lag0) & (LQ - 1)] + w1 * xs_[(l - lag1) & (LQ - 1)];
            float var = xv * xv * Mxx + xsv * xsv * Mss + Mcc
                      + 2.f * xv * xsv * Mxs + 2.f * xv * Mxc + 2.f * xsv * Msc;
            float r = rsqrtf(var + LN_EPS);
            acc += (xv * r) * Fpu[l] + (xsv * r) * Fpv[l] + r * Fpw[l] + FBp[l];
        }
        acc = wave_sum64(acc);
        if ((tid & 63) == 0) red[wv] = acc;
    }
    __syncthreads();
    if (tid == 0) {
        float s = 0.f;
#pragma unroll
        for (int w = 0; w < 16; ++w) s += red[w];
        out[b] = s + fc_b[0];
    }
}

extern "C" void kernel_launch(void* const* d_in, const int* in_sizes, int n_in,
                              void* d_out, int out_size, void* d_ws, size_t ws_size,
                              hipStream_t stream) {
    const float* x       = (const float*)d_in[0];
    const float* embed_w = (const float*)d_in[1];
    const float* embed_b = (const float*)d_in[2];
    const float* q_w     = (const float*)d_in[3];
    const float* q_b     = (const float*)d_in[4];
    const float* k_w     = (const float*)d_in[5];
    const float* k_b     = (const float*)d_in[6];
    const float* v_w     = (const float*)d_in[7];
    const float* v_b     = (const float*)d_in[8];
    const float* ln_g    = (const float*)d_in[9];
    const float* ln_b    = (const float*)d_in[10];
    const float* fc_w    = (const float*)d_in[11];
    const float* fc_b    = (const float*)d_in[12];
    float* out = (float*)d_out;
    float* ws  = (float*)d_ws;

    ac_stage1_kernel<<<NBLK, 256, 0, stream>>>(x, fc_w, ln_g, ln_b,
                                               embed_w, embed_b,
                                               q_w, q_b, k_w, k_b, v_w, v_b, ws);
    ac_final_kernel<<<BQ, 1024, 0, stream>>>(x, fc_b, ws, out);
}